// Round 1
// baseline (680.873 us; speedup 1.0000x reference)
//
#include <hip/hip_runtime.h>
#include <hip/hip_bf16.h>
#include <cstdint>
#include <cstddef>

#define NN 20000
#define KK 32
#define HH 128
#define FFD 512
#define LN_EPS 1e-5f

typedef __attribute__((ext_vector_type(8))) short bf16x8;
typedef __attribute__((ext_vector_type(4))) float f32x4;

__device__ __forceinline__ short f2b(float f){
  __hip_bfloat16 h = __float2bfloat16(f);
  return __builtin_bit_cast(short, h);
}
__device__ __forceinline__ float b2f(short s){
  union { unsigned int u; float f; } v; v.u = ((unsigned int)(unsigned short)s) << 16; return v.f;
}
__device__ __forceinline__ float gelu_f(float x){
  return 0.5f*x*(1.0f + erff(x*0.70710678118654752f));
}
__device__ __forceinline__ f32x4 MFMA(bf16x8 a, bf16x8 b, f32x4 c){
  return __builtin_amdgcn_mfma_f32_16x16x32_bf16(a, b, c, 0, 0, 0);
}

// ---------------- weight packing ----------------
// pk layout: 10 x [128x128] slots (16384 shorts each):
//  0:W1a 1:W1c 2:W1b 3:W2 4:W3 5:W11a 6:W11c 7:W11b 8:W12 9:W13
// then Win (128x512) at 163840, Wout (512x128) at 229376. total 294912 shorts.
// B-fragment packing for mfma 16x16x32: element (k,n) ->
//   ((kt*NT+nt)*64 + lane)*8 + j ; lane = ((k>>3)&3)*16 + (n&15), j = k&7
__global__ __launch_bounds__(256) void enc_pack(
    const float* __restrict__ W1, const float* __restrict__ W2, const float* __restrict__ W3,
    const float* __restrict__ W11, const float* __restrict__ W12, const float* __restrict__ W13,
    const float* __restrict__ Win, const float* __restrict__ Wout,
    short* __restrict__ pk)
{
  const int stride = gridDim.x * blockDim.x;
  for (int idx = blockIdx.x*blockDim.x + threadIdx.x; idx < 294912; idx += stride){
    const float* src = W2; int srow = 0, k, n, NT, NCOLS, base;
    if (idx < 163840){
      int slot = idx >> 14, e = idx & 16383;
      k = e >> 7; n = e & 127; NT = 8; NCOLS = 128; base = slot << 14;
      switch (slot){
        case 0: src = W1;  srow = 0;   break;
        case 1: src = W1;  srow = 256; break;
        case 2: src = W1;  srow = 128; break;
        case 3: src = W2;  srow = 0;   break;
        case 4: src = W3;  srow = 0;   break;
        case 5: src = W11; srow = 0;   break;
        case 6: src = W11; srow = 256; break;
        case 7: src = W11; srow = 128; break;
        case 8: src = W12; srow = 0;   break;
        default: src = W13; srow = 0;  break;
      }
    } else if (idx < 229376){
      int e = idx - 163840; k = e >> 9; n = e & 511; NT = 32; NCOLS = 512; src = Win; base = 163840;
    } else {
      int e = idx - 229376; k = e >> 7; n = e & 127; NT = 8; NCOLS = 128; src = Wout; base = 229376;
    }
    float v = src[(srow + k)*NCOLS + n];
    int out = base + (((k>>5)*NT + (n>>4))*64 + ((k>>3)&3)*16 + (n&15))*8 + (k&7);
    pk[out] = f2b(v);
  }
}

// ---------------- node projections: U = X@Wa + b, Z = X@Wc ----------------
__global__ __launch_bounds__(256, 2) void enc_proj(
    const float* __restrict__ X, const short* __restrict__ pkU, const short* __restrict__ pkZ,
    const float* __restrict__ biasU, short* __restrict__ U, short* __restrict__ Z)
{
  const int lane = threadIdx.x & 63, w = threadIdx.x >> 6;
  const int kgrp = lane >> 4, ccol = lane & 15;
  const int row0 = blockIdx.x*64 + w*16;
  const int arow = row0 + (lane & 15);
  f32x4 accU[8], accZ[8];
  #pragma unroll
  for (int nf=0;nf<8;nf++){ accU[nf] = (f32x4){0,0,0,0}; accZ[nf] = (f32x4){0,0,0,0}; }
  #pragma unroll
  for (int kt=0;kt<4;kt++){
    bf16x8 af = {0,0,0,0,0,0,0,0};
    if (arow < NN){
      const float4* p = (const float4*)(X + (size_t)arow*HH + kt*32 + kgrp*8);
      float4 v0 = p[0], v1 = p[1];
      af[0]=f2b(v0.x); af[1]=f2b(v0.y); af[2]=f2b(v0.z); af[3]=f2b(v0.w);
      af[4]=f2b(v1.x); af[5]=f2b(v1.y); af[6]=f2b(v1.z); af[7]=f2b(v1.w);
    }
    #pragma unroll
    for (int nf=0;nf<8;nf++){
      bf16x8 bu = *(const bf16x8*)(pkU + (((kt<<3)+nf)*64 + lane)*8);
      accU[nf] = MFMA(af, bu, accU[nf]);
      bf16x8 bz = *(const bf16x8*)(pkZ + (((kt<<3)+nf)*64 + lane)*8);
      accZ[nf] = MFMA(af, bz, accZ[nf]);
    }
  }
  #pragma unroll
  for (int nf=0;nf<8;nf++){
    #pragma unroll
    for (int r=0;r<4;r++){
      int grow = row0 + kgrp*4 + r;
      if (grow < NN){
        int col = nf*16 + ccol;
        U[(size_t)grow*HH + col] = f2b(accU[nf][r] + biasU[col]);
        Z[(size_t)grow*HH + col] = f2b(accZ[nf][r]);
      }
    }
  }
}

// ---------------- fused 3-layer edge MLP ----------------
// PASS 0: node update  -> mask*msg, aggregate over K, +h_V, LN1 -> hVmid [N,H]
// PASS 1: edge update  -> + h_E residual, LN3 -> d_out.hE
// block = 2 nodes = 64 edge rows, 4 waves; wave w owns rows [w*16, w*16+16)
#define LSTR 136   // padded LDS row stride (shorts); 272B, multiple of 16B
template<int PASS>
__global__ __launch_bounds__(256, 3) void enc_mlp3(
    const float* __restrict__ hE,
    const short* __restrict__ Ub, const short* __restrict__ Zb,
    const int*  __restrict__ Eidx,
    const float* __restrict__ maskAtt,
    const float* __restrict__ hV,
    const float* __restrict__ lnG, const float* __restrict__ lnB,
    const short* __restrict__ pkL1,
    const short* __restrict__ pkL2, const float* __restrict__ bias2,
    const short* __restrict__ pkL3, const float* __restrict__ bias3,
    float* __restrict__ outP)
{
  __shared__ __align__(16) char smem[53568];
  short* bufA = (short*)smem;                 // [64][136]
  short* bufB = (short*)(smem + 17408);       // [64][136]
  short* sZg  = (short*)(smem + 34816);       // [64][136]
  float* sU   = (float*)(smem + 52224);       // [2][128]
  float* sMask= (float*)(smem + 53248);       // [64]
  float* sRed = (float*)(smem + 53504);       // [16]

  const int i0 = blockIdx.x*2;
  const int t = threadIdx.x;

  // stage hE tile (64 rows x 128) fp32 -> bf16
  {
    const float4* src = (const float4*)(hE + (size_t)i0*KK*HH);
    #pragma unroll
    for (int it=0; it<8; it++){
      int idx = it*256 + t;
      int r = idx >> 5, c4 = idx & 31;
      float4 v = src[idx];
      short* d = bufA + r*LSTR + c4*4;
      d[0]=f2b(v.x); d[1]=f2b(v.y); d[2]=f2b(v.z); d[3]=f2b(v.w);
    }
  }
  // gather Z rows for the 64 edges (16B per lane)
  #pragma unroll
  for (int it=0; it<4; it++){
    int r = it*16 + (t >> 4);
    int seg = t & 15;
    int j = Eidx[i0*KK + r];
    *(int4*)(sZg + r*LSTR + seg*8) = *(const int4*)(Zb + (size_t)j*HH + seg*8);
  }
  { // U rows (2 nodes)
    int g = t >> 7, c = t & 127;
    sU[g*128 + c] = b2f(Ub[(size_t)(i0+g)*HH + c]);
  }
  if (PASS == 0 && t < 64) sMask[t] = maskAtt[i0*KK + t];
  __syncthreads();

  const int lane = t & 63, w = t >> 6;
  const int kgrp = lane >> 4, ccol = lane & 15;
  const int arow = w*16 + (lane & 15);
  f32x4 acc[8];

  // ---- layer 1: hE @ W_b  (+U +Z, gelu) ----
  #pragma unroll
  for (int nf=0;nf<8;nf++) acc[nf] = (f32x4){0,0,0,0};
  #pragma unroll
  for (int kt=0;kt<4;kt++){
    bf16x8 af = *(const bf16x8*)(bufA + arow*LSTR + kt*32 + kgrp*8);
    #pragma unroll
    for (int nf=0;nf<8;nf++){
      bf16x8 b = *(const bf16x8*)(pkL1 + (((kt<<3)+nf)*64 + lane)*8);
      acc[nf] = MFMA(af, b, acc[nf]);
    }
  }
  #pragma unroll
  for (int nf=0;nf<8;nf++){
    #pragma unroll
    for (int r=0;r<4;r++){
      int row = w*16 + kgrp*4 + r, col = nf*16 + ccol;
      float v = acc[nf][r] + sU[(row>>5)*128 + col] + b2f(sZg[row*LSTR + col]);
      bufB[row*LSTR + col] = f2b(gelu_f(v));
    }
  }
  // ---- layer 2: msg1 @ W2 (+b2, gelu) ----  (wave-local rows; no barrier needed)
  #pragma unroll
  for (int nf=0;nf<8;nf++) acc[nf] = (f32x4){0,0,0,0};
  #pragma unroll
  for (int kt=0;kt<4;kt++){
    bf16x8 af = *(const bf16x8*)(bufB + arow*LSTR + kt*32 + kgrp*8);
    #pragma unroll
    for (int nf=0;nf<8;nf++){
      bf16x8 b = *(const bf16x8*)(pkL2 + (((kt<<3)+nf)*64 + lane)*8);
      acc[nf] = MFMA(af, b, acc[nf]);
    }
  }
  #pragma unroll
  for (int nf=0;nf<8;nf++){
    #pragma unroll
    for (int r=0;r<4;r++){
      int row = w*16 + kgrp*4 + r, col = nf*16 + ccol;
      float v = acc[nf][r] + bias2[col];
      bufA[row*LSTR + col] = f2b(gelu_f(v));
    }
  }
  // ---- layer 3: msg2 @ W3 ----
  #pragma unroll
  for (int nf=0;nf<8;nf++) acc[nf] = (f32x4){0,0,0,0};
  #pragma unroll
  for (int kt=0;kt<4;kt++){
    bf16x8 af = *(const bf16x8*)(bufA + arow*LSTR + kt*32 + kgrp*8);
    #pragma unroll
    for (int nf=0;nf<8;nf++){
      bf16x8 b = *(const bf16x8*)(pkL3 + (((kt<<3)+nf)*64 + lane)*8);
      acc[nf] = MFMA(af, b, acc[nf]);
    }
  }

  if (PASS == 0){
    // mask, write msg3 to LDS (overlays bufA+bufB), aggregate per node, LN1
    __syncthreads();                 // all layer-3 A reads done before overlay
    float* sMsg = (float*)smem;      // [64][128]
    #pragma unroll
    for (int nf=0;nf<8;nf++){
      #pragma unroll
      for (int r=0;r<4;r++){
        int row = w*16 + kgrp*4 + r, col = nf*16 + ccol;
        sMsg[row*128 + col] = (acc[nf][r] + bias3[col]) * sMask[row];
      }
    }
    __syncthreads();
    int g = t >> 7, c = t & 127;
    float s = 0.f;
    #pragma unroll
    for (int k=0;k<32;k++) s += sMsg[(g*32 + k)*128 + c];
    float x = hV[(size_t)(i0+g)*HH + c] + s*(1.0f/30.0f);
    float sm = x, sq = x*x;
    #pragma unroll
    for (int off=1; off<64; off<<=1){
      sm += __shfl_xor(sm, off);
      sq += __shfl_xor(sq, off);
    }
    if (lane == 0){ sRed[w*2] = sm; sRed[w*2+1] = sq; }
    __syncthreads();
    sm += sRed[(w^1)*2]; sq += sRed[(w^1)*2+1];
    float mean = sm*(1.f/128.f);
    float var  = sq*(1.f/128.f) - mean*mean;
    float o = (x - mean)*rsqrtf(var + LN_EPS)*lnG[c] + lnB[c];
    outP[(size_t)(i0+g)*HH + c] = o;
  } else {
    // +b13, +h_E residual, LN3 fully in-register (row = 16-lane group)
    float rsum[4] = {0,0,0,0}, rsq[4] = {0,0,0,0};
    #pragma unroll
    for (int nf=0;nf<8;nf++){
      #pragma unroll
      for (int r=0;r<4;r++){
        int row = w*16 + kgrp*4 + r, col = nf*16 + ccol;
        float x = acc[nf][r] + bias3[col] + hE[((size_t)(i0*KK + row))*HH + col];
        acc[nf][r] = x;
        rsum[r] += x; rsq[r] += x*x;
      }
    }
    #pragma unroll
    for (int off=1; off<16; off<<=1){
      #pragma unroll
      for (int r=0;r<4;r++){
        rsum[r] += __shfl_xor(rsum[r], off);
        rsq[r]  += __shfl_xor(rsq[r], off);
      }
    }
    #pragma unroll
    for (int r=0;r<4;r++){
      float mean = rsum[r]*(1.f/128.f);
      float var  = rsq[r]*(1.f/128.f) - mean*mean;
      float inv  = rsqrtf(var + LN_EPS);
      #pragma unroll
      for (int nf=0;nf<8;nf++){
        int row = w*16 + kgrp*4 + r, col = nf*16 + ccol;
        outP[((size_t)(i0*KK + row))*HH + col] = (acc[nf][r]-mean)*inv*lnG[col] + lnB[col];
      }
    }
  }
}

// ---------------- fused FFN 128->512->128 + LN2 + mask_V ----------------
__global__ __launch_bounds__(256, 2) void enc_ffn(
    const float* __restrict__ X,                 // hVmid [N,128]
    const short* __restrict__ pkWin, const float* __restrict__ bin,
    const short* __restrict__ pkWout, const float* __restrict__ bout,
    const float* __restrict__ g2, const float* __restrict__ b2ln,
    const float* __restrict__ maskV,
    float* __restrict__ out)
{
  __shared__ short sT[64*512];   // XOR-swizzled: elem col ^ ((row&7)<<3)
  const int t = threadIdx.x, lane = t & 63, w = t >> 6;
  const int kgrp = lane >> 4, ccol = lane & 15;
  const int row0 = blockIdx.x*64;
  const int arow = row0 + w*16 + (lane & 15);
  // phase 1: T = gelu(X@Win + bin)
  f32x4 acc[32];
  #pragma unroll
  for (int nf=0;nf<32;nf++) acc[nf] = (f32x4){0,0,0,0};
  #pragma unroll
  for (int kt=0;kt<4;kt++){
    bf16x8 af = {0,0,0,0,0,0,0,0};
    if (arow < NN){
      const float4* p = (const float4*)(X + (size_t)arow*HH + kt*32 + kgrp*8);
      float4 v0 = p[0], v1 = p[1];
      af[0]=f2b(v0.x); af[1]=f2b(v0.y); af[2]=f2b(v0.z); af[3]=f2b(v0.w);
      af[4]=f2b(v1.x); af[5]=f2b(v1.y); af[6]=f2b(v1.z); af[7]=f2b(v1.w);
    }
    #pragma unroll
    for (int nf=0;nf<32;nf++){
      bf16x8 b = *(const bf16x8*)(pkWin + ((size_t)((kt<<5)+nf)*64 + lane)*8);
      acc[nf] = MFMA(af, b, acc[nf]);
    }
  }
  #pragma unroll
  for (int nf=0;nf<32;nf++){
    #pragma unroll
    for (int r=0;r<4;r++){
      int rl = w*16 + kgrp*4 + r, col = nf*16 + ccol;
      sT[rl*512 + (col ^ ((rl&7)<<3))] = f2b(gelu_f(acc[nf][r] + bin[col]));
    }
  }
  // phase 2: out = T@Wout + bout, residual + LN2 + mask  (wave-local rows)
  f32x4 a2[8];
  #pragma unroll
  for (int nf=0;nf<8;nf++) a2[nf] = (f32x4){0,0,0,0};
  const int rl_a = w*16 + (lane & 15);
  #pragma unroll
  for (int kt=0;kt<16;kt++){
    int base = kt*32 + kgrp*8;
    bf16x8 af = *(const bf16x8*)(sT + rl_a*512 + (base ^ ((rl_a&7)<<3)));
    #pragma unroll
    for (int nf=0;nf<8;nf++){
      bf16x8 b = *(const bf16x8*)(pkWout + (((kt<<3)+nf)*64 + lane)*8);
      a2[nf] = MFMA(af, b, a2[nf]);
    }
  }
  float rsum[4] = {0,0,0,0}, rsq[4] = {0,0,0,0};
  #pragma unroll
  for (int nf=0;nf<8;nf++){
    #pragma unroll
    for (int r=0;r<4;r++){
      int grow = row0 + w*16 + kgrp*4 + r, col = nf*16 + ccol;
      float prev = (grow < NN) ? X[(size_t)grow*HH + col] : 0.f;
      float x = a2[nf][r] + bout[col] + prev;
      a2[nf][r] = x;
      rsum[r] += x; rsq[r] += x*x;
    }
  }
  #pragma unroll
  for (int off=1; off<16; off<<=1){
    #pragma unroll
    for (int r=0;r<4;r++){
      rsum[r] += __shfl_xor(rsum[r], off);
      rsq[r]  += __shfl_xor(rsq[r], off);
    }
  }
  #pragma unroll
  for (int r=0;r<4;r++){
    int grow = row0 + w*16 + kgrp*4 + r;
    float mean = rsum[r]*(1.f/128.f);
    float var  = rsq[r]*(1.f/128.f) - mean*mean;
    float inv  = rsqrtf(var + LN_EPS);
    float mv   = (grow < NN) ? maskV[grow] : 0.f;
    #pragma unroll
    for (int nf=0;nf<8;nf++){
      int col = nf*16 + ccol;
      if (grow < NN)
        out[(size_t)grow*HH + col] = mv * ((a2[nf][r]-mean)*inv*g2[col] + b2ln[col]);
    }
  }
}

// ---------------- host ----------------
extern "C" void kernel_launch(void* const* d_in, const int* in_sizes, int n_in,
                              void* d_out, int out_size, void* d_ws, size_t ws_size,
                              hipStream_t stream)
{
  const float* h_V   = (const float*)d_in[0];
  const float* h_E   = (const float*)d_in[1];
  const float* maskV = (const float*)d_in[2];
  const float* maskA = (const float*)d_in[3];
  const float* W1w  = (const float*)d_in[4];  const float* W1b  = (const float*)d_in[5];
  const float* W2w  = (const float*)d_in[6];  const float* W2b  = (const float*)d_in[7];
  const float* W3w  = (const float*)d_in[8];  const float* W3b  = (const float*)d_in[9];
  const float* W11w = (const float*)d_in[10]; const float* W11b = (const float*)d_in[11];
  const float* W12w = (const float*)d_in[12]; const float* W12b = (const float*)d_in[13];
  const float* W13w = (const float*)d_in[14]; const float* W13b = (const float*)d_in[15];
  const float* Winw = (const float*)d_in[16]; const float* Winb = (const float*)d_in[17];
  const float* Woutw= (const float*)d_in[18]; const float* Woutb= (const float*)d_in[19];
  const float* ln1g = (const float*)d_in[20]; const float* ln1b = (const float*)d_in[21];
  const float* ln2g = (const float*)d_in[22]; const float* ln2b = (const float*)d_in[23];
  const float* ln3g = (const float*)d_in[24]; const float* ln3b = (const float*)d_in[25];
  const int*   Eidx = (const int*)d_in[26];

  float* outV = (float*)d_out;                     // [N,128]
  float* outE = outV + (size_t)NN*HH;              // [N,K,128]

  char* ws = (char*)d_ws;
  short* pk = (short*)ws;
  const short* pkW1a  = pk + 0*16384;
  const short* pkW1c  = pk + 1*16384;
  const short* pkW1bb = pk + 2*16384;
  const short* pkW2   = pk + 3*16384;
  const short* pkW3   = pk + 4*16384;
  const short* pkW11a = pk + 5*16384;
  const short* pkW11c = pk + 6*16384;
  const short* pkW11bb= pk + 7*16384;
  const short* pkW12  = pk + 8*16384;
  const short* pkW13  = pk + 9*16384;
  const short* pkWin  = pk + 163840;
  const short* pkWout = pk + 229376;

  short* U1 = (short*)(ws + 1048576);
  short* Z1 = (short*)(ws + 6291456);
  short* U2 = (short*)(ws + 11534336);
  short* Z2 = (short*)(ws + 16777216);
  float* hVmid = (float*)(ws + 22020096);

  enc_pack<<<288, 256, 0, stream>>>(W1w, W2w, W3w, W11w, W12w, W13w, Winw, Woutw, pk);
  enc_proj<<<313, 256, 0, stream>>>(h_V, pkW1a, pkW1c, W1b, U1, Z1);
  enc_mlp3<0><<<NN/2, 256, 0, stream>>>(h_E, U1, Z1, Eidx, maskA, h_V,
                                        ln1g, ln1b, pkW1bb, pkW2, W2b, pkW3, W3b, hVmid);
  enc_ffn<<<313, 256, 0, stream>>>(hVmid, pkWin, Winb, pkWout, Woutb,
                                   ln2g, ln2b, maskV, outV);
  enc_proj<<<313, 256, 0, stream>>>(outV, pkW11a, pkW11c, W11b, U2, Z2);
  enc_mlp3<1><<<NN/2, 256, 0, stream>>>(h_E, U2, Z2, Eidx, nullptr, nullptr,
                                        ln3g, ln3b, pkW11bb, pkW12, W12b, pkW13, W13b, outE);
}

// Round 2
// 536.761 us; speedup vs baseline: 1.2685x; 1.2685x over previous
//
#include <hip/hip_runtime.h>
#include <hip/hip_bf16.h>
#include <cstdint>
#include <cstddef>

#define NN 20000
#define KK 32
#define HH 128
#define FFD 512
#define LN_EPS 1e-5f

typedef __attribute__((ext_vector_type(8))) short bf16x8;
typedef __attribute__((ext_vector_type(4))) float f32x4;

__device__ __forceinline__ short f2b(float f){
  __hip_bfloat16 h = __float2bfloat16(f);
  return __builtin_bit_cast(short, h);
}
__device__ __forceinline__ float b2f(short s){
  union { unsigned int u; float f; } v; v.u = ((unsigned int)(unsigned short)s) << 16; return v.f;
}
// tanh-form GELU via hw exp2 + rcp:  gelu(x) = x - x / (1 + 2^(x*(C0 + C1*x^2)))
// C0 = sqrt(2/pi)*2*log2(e), C1 = C0*0.044715
__device__ __forceinline__ float gelu_fast(float x){
  float u = x * __builtin_fmaf(0.10294278f, x*x, 2.3022082f);
  float e = __builtin_amdgcn_exp2f(u);
  float r = __builtin_amdgcn_rcpf(1.0f + e);
  return __builtin_fmaf(-x, r, x);
}
__device__ __forceinline__ f32x4 MFMA(bf16x8 a, bf16x8 b, f32x4 c){
  return __builtin_amdgcn_mfma_f32_16x16x32_bf16(a, b, c, 0, 0, 0);
}

// ---------------- weight packing ----------------
// pk layout: 10 x [128x128] slots (16384 shorts each):
//  0:W1a 1:W1c 2:W1b 3:W2 4:W3 5:W11a 6:W11c 7:W11b 8:W12 9:W13
// then Win (128x512) at 163840, Wout (512x128) at 229376. total 294912 shorts.
// B-fragment packing for mfma 16x16x32: element (k,n) ->
//   ((kt*NT+nt)*64 + lane)*8 + j ; lane = ((k>>3)&3)*16 + (n&15), j = k&7
__global__ __launch_bounds__(256) void enc_pack(
    const float* __restrict__ W1, const float* __restrict__ W2, const float* __restrict__ W3,
    const float* __restrict__ W11, const float* __restrict__ W12, const float* __restrict__ W13,
    const float* __restrict__ Win, const float* __restrict__ Wout,
    short* __restrict__ pk)
{
  const int stride = gridDim.x * blockDim.x;
  for (int idx = blockIdx.x*blockDim.x + threadIdx.x; idx < 294912; idx += stride){
    const float* src = W2; int srow = 0, k, n, NT, NCOLS, base;
    if (idx < 163840){
      int slot = idx >> 14, e = idx & 16383;
      k = e >> 7; n = e & 127; NT = 8; NCOLS = 128; base = slot << 14;
      switch (slot){
        case 0: src = W1;  srow = 0;   break;
        case 1: src = W1;  srow = 256; break;
        case 2: src = W1;  srow = 128; break;
        case 3: src = W2;  srow = 0;   break;
        case 4: src = W3;  srow = 0;   break;
        case 5: src = W11; srow = 0;   break;
        case 6: src = W11; srow = 256; break;
        case 7: src = W11; srow = 128; break;
        case 8: src = W12; srow = 0;   break;
        default: src = W13; srow = 0;  break;
      }
    } else if (idx < 229376){
      int e = idx - 163840; k = e >> 9; n = e & 511; NT = 32; NCOLS = 512; src = Win; base = 163840;
    } else {
      int e = idx - 229376; k = e >> 7; n = e & 127; NT = 8; NCOLS = 128; src = Wout; base = 229376;
    }
    float v = src[(srow + k)*NCOLS + n];
    int out = base + (((k>>5)*NT + (n>>4))*64 + ((k>>3)&3)*16 + (n&15))*8 + (k&7);
    pk[out] = f2b(v);
  }
}

// ---------------- node projections: U = X@Wa + b, Z = X@Wc ----------------
__global__ __launch_bounds__(256, 2) void enc_proj(
    const float* __restrict__ X, const short* __restrict__ pkU, const short* __restrict__ pkZ,
    const float* __restrict__ biasU, short* __restrict__ U, short* __restrict__ Z)
{
  const int lane = threadIdx.x & 63, w = threadIdx.x >> 6;
  const int kgrp = lane >> 4, ccol = lane & 15;
  const int row0 = blockIdx.x*64 + w*16;
  const int arow = row0 + (lane & 15);
  f32x4 accU[8], accZ[8];
  #pragma unroll
  for (int nf=0;nf<8;nf++){ accU[nf] = (f32x4){0,0,0,0}; accZ[nf] = (f32x4){0,0,0,0}; }
  #pragma unroll
  for (int kt=0;kt<4;kt++){
    bf16x8 af = {0,0,0,0,0,0,0,0};
    if (arow < NN){
      const float4* p = (const float4*)(X + (size_t)arow*HH + kt*32 + kgrp*8);
      float4 v0 = p[0], v1 = p[1];
      af[0]=f2b(v0.x); af[1]=f2b(v0.y); af[2]=f2b(v0.z); af[3]=f2b(v0.w);
      af[4]=f2b(v1.x); af[5]=f2b(v1.y); af[6]=f2b(v1.z); af[7]=f2b(v1.w);
    }
    #pragma unroll
    for (int nf=0;nf<8;nf++){
      bf16x8 bu = *(const bf16x8*)(pkU + (((kt<<3)+nf)*64 + lane)*8);
      accU[nf] = MFMA(af, bu, accU[nf]);
      bf16x8 bz = *(const bf16x8*)(pkZ + (((kt<<3)+nf)*64 + lane)*8);
      accZ[nf] = MFMA(af, bz, accZ[nf]);
    }
  }
  #pragma unroll
  for (int nf=0;nf<8;nf++){
    #pragma unroll
    for (int r=0;r<4;r++){
      int grow = row0 + kgrp*4 + r;
      if (grow < NN){
        int col = nf*16 + ccol;
        U[(size_t)grow*HH + col] = f2b(accU[nf][r] + biasU[col]);
        Z[(size_t)grow*HH + col] = f2b(accZ[nf][r]);
      }
    }
  }
}

// ---------------- fused 3-layer edge MLP ----------------
// PASS 0: node update  -> mask*msg, aggregate over K, +h_V, LN1 -> hVmid [N,H]
// PASS 1: edge update  -> + h_E residual, LN3 -> d_out.hE
// block = 2 nodes = 64 edge rows, 4 waves; wave w owns rows [w*16, w*16+16)
// All staging/compute wave-local: PASS1 has no barriers; PASS0 barriers only at tail.
#define LSTR 136   // padded LDS row stride (shorts); 272B = 17*16B
template<int PASS>
__global__ __launch_bounds__(256, 4) void enc_mlp3(
    const float* __restrict__ hE,
    const short* __restrict__ Ub, const short* __restrict__ Zb,
    const int*  __restrict__ Eidx,
    const float* __restrict__ maskAtt,
    const float* __restrict__ hV,
    const float* __restrict__ lnG, const float* __restrict__ lnB,
    const short* __restrict__ pkL1,
    const short* __restrict__ pkL2, const float* __restrict__ bias2,
    const short* __restrict__ pkL3, const float* __restrict__ bias3,
    float* __restrict__ outP)
{
  __shared__ __align__(16) char smem[34880];
  short* bufA = (short*)smem;                 // [64][136]
  short* bufB = (short*)(smem + 17408);       // [64][136]
  float* sRed = (float*)(smem + 34816);       // [16]

  const int i0 = blockIdx.x*2;
  const int t = threadIdx.x;
  const int lane = t & 63, w = t >> 6;
  const int kgrp = lane >> 4, ccol = lane & 15;
  const int g = w >> 1;            // node within block for this wave's rows
  const int rw = w*16;             // wave's first edge-row in block

  // ---- issue gathers early (latency hidden under staging + layer 1) ----
  const int zrow = rw + (lane >> 2);              // wave-local row 0..15
  const int seg0 = lane & 3;
  const int j = Eidx[i0*KK + zrow];
  int4 zreg[4];
  const int4* zsrc = (const int4*)(Zb + (size_t)j*HH);
  #pragma unroll
  for (int s=0; s<4; s++) zreg[s] = zsrc[seg0 + 4*s];

  float ureg[8], b2reg[8], b3reg[8];
  #pragma unroll
  for (int nf=0; nf<8; nf++){
    int col = nf*16 + ccol;
    ureg[nf]  = b2f(Ub[(size_t)(i0+g)*HH + col]);
    b2reg[nf] = bias2[col];
    b3reg[nf] = bias3[col];
  }
  float mreg[4] = {0,0,0,0};
  if (PASS == 0){
    const float4 mv = *(const float4*)(maskAtt + i0*KK + rw + kgrp*4);
    mreg[0]=mv.x; mreg[1]=mv.y; mreg[2]=mv.z; mreg[3]=mv.w;
  }

  // ---- stage hE rows rw..rw+15 (wave-local) fp32 -> bf16 ----
  {
    const float4* src = (const float4*)(hE + ((size_t)i0*KK + rw)*HH);
    #pragma unroll
    for (int it=0; it<8; it++){
      int r = it*2 + (lane>>5);      // 0..15
      int c4 = lane & 31;
      float4 v = src[r*32 + c4];
      uint2 p;
      p.x = (uint)(unsigned short)f2b(v.x) | ((uint)(unsigned short)f2b(v.y) << 16);
      p.y = (uint)(unsigned short)f2b(v.z) | ((uint)(unsigned short)f2b(v.w) << 16);
      *(uint2*)(bufA + (rw + r)*LSTR + c4*4) = p;
    }
  }

  const int arow = rw + ccol;
  f32x4 acc[8];

  // ---- layer 1: hE @ W_b  (acc init = U; then +Z, gelu) ----
  #pragma unroll
  for (int nf=0;nf<8;nf++) acc[nf] = (f32x4){ureg[nf],ureg[nf],ureg[nf],ureg[nf]};
  #pragma unroll
  for (int kt=0;kt<4;kt++){
    bf16x8 af = *(const bf16x8*)(bufA + arow*LSTR + kt*32 + kgrp*8);
    #pragma unroll
    for (int nf=0;nf<8;nf++){
      bf16x8 b = *(const bf16x8*)(pkL1 + (((kt<<3)+nf)*64 + lane)*8);
      acc[nf] = MFMA(af, b, acc[nf]);
    }
  }
  // deferred Z write into bufA (wave-private rows; hE fragments already consumed)
  #pragma unroll
  for (int s=0;s<4;s++)
    *(int4*)(bufA + zrow*LSTR + (seg0 + 4*s)*8) = zreg[s];

  #pragma unroll
  for (int nf=0;nf<8;nf++){
    #pragma unroll
    for (int r=0;r<4;r++){
      int row = rw + kgrp*4 + r, col = nf*16 + ccol;
      float v = acc[nf][r] + b2f(bufA[row*LSTR + col]);
      bufB[row*LSTR + col] = f2b(gelu_fast(v));
    }
  }
  // ---- layer 2: msg1 @ W2 (acc init = b2, gelu) ----
  #pragma unroll
  for (int nf=0;nf<8;nf++) acc[nf] = (f32x4){b2reg[nf],b2reg[nf],b2reg[nf],b2reg[nf]};
  #pragma unroll
  for (int kt=0;kt<4;kt++){
    bf16x8 af = *(const bf16x8*)(bufB + arow*LSTR + kt*32 + kgrp*8);
    #pragma unroll
    for (int nf=0;nf<8;nf++){
      bf16x8 b = *(const bf16x8*)(pkL2 + (((kt<<3)+nf)*64 + lane)*8);
      acc[nf] = MFMA(af, b, acc[nf]);
    }
  }
  #pragma unroll
  for (int nf=0;nf<8;nf++){
    #pragma unroll
    for (int r=0;r<4;r++){
      int row = rw + kgrp*4 + r, col = nf*16 + ccol;
      bufA[row*LSTR + col] = f2b(gelu_fast(acc[nf][r]));
    }
  }
  // ---- layer 3: msg2 @ W3 (acc init = b3) ----
  #pragma unroll
  for (int nf=0;nf<8;nf++) acc[nf] = (f32x4){b3reg[nf],b3reg[nf],b3reg[nf],b3reg[nf]};
  #pragma unroll
  for (int kt=0;kt<4;kt++){
    bf16x8 af = *(const bf16x8*)(bufA + arow*LSTR + kt*32 + kgrp*8);
    #pragma unroll
    for (int nf=0;nf<8;nf++){
      bf16x8 b = *(const bf16x8*)(pkL3 + (((kt<<3)+nf)*64 + lane)*8);
      acc[nf] = MFMA(af, b, acc[nf]);
    }
  }

  if (PASS == 0){
    // mask, write msg3 to LDS (overlays bufA+bufB), aggregate per node, LN1
    __syncthreads();                 // all layer-3 A reads done before overlay
    float* sMsg = (float*)smem;      // [64][128]
    #pragma unroll
    for (int nf=0;nf<8;nf++){
      #pragma unroll
      for (int r=0;r<4;r++){
        int row = rw + kgrp*4 + r, col = nf*16 + ccol;
        sMsg[row*128 + col] = acc[nf][r] * mreg[r];
      }
    }
    __syncthreads();
    int gg = t >> 7, c = t & 127;
    float s = 0.f;
    #pragma unroll
    for (int k=0;k<32;k++) s += sMsg[(gg*32 + k)*128 + c];
    float x = hV[(size_t)(i0+gg)*HH + c] + s*(1.0f/30.0f);
    float sm = x, sq = x*x;
    #pragma unroll
    for (int off=1; off<64; off<<=1){
      sm += __shfl_xor(sm, off);
      sq += __shfl_xor(sq, off);
    }
    if (lane == 0){ sRed[w*2] = sm; sRed[w*2+1] = sq; }
    __syncthreads();
    sm += sRed[(w^1)*2]; sq += sRed[(w^1)*2+1];
    float mean = sm*(1.f/128.f);
    float var  = sq*(1.f/128.f) - mean*mean;
    float o = (x - mean)*rsqrtf(var + LN_EPS)*lnG[c] + lnB[c];
    outP[(size_t)(i0+gg)*HH + c] = o;
  } else {
    // + h_E residual, LN3 fully in-register (row = 16-lane group)
    float rsum[4] = {0,0,0,0}, rsq[4] = {0,0,0,0};
    #pragma unroll
    for (int nf=0;nf<8;nf++){
      #pragma unroll
      for (int r=0;r<4;r++){
        int row = rw + kgrp*4 + r, col = nf*16 + ccol;
        float x = acc[nf][r] + hE[((size_t)(i0*KK + row))*HH + col];
        acc[nf][r] = x;
        rsum[r] += x; rsq[r] += x*x;
      }
    }
    #pragma unroll
    for (int off=1; off<16; off<<=1){
      #pragma unroll
      for (int r=0;r<4;r++){
        rsum[r] += __shfl_xor(rsum[r], off);
        rsq[r]  += __shfl_xor(rsq[r], off);
      }
    }
    #pragma unroll
    for (int r=0;r<4;r++){
      float mean = rsum[r]*(1.f/128.f);
      float var  = rsq[r]*(1.f/128.f) - mean*mean;
      float inv  = rsqrtf(var + LN_EPS);
      #pragma unroll
      for (int nf=0;nf<8;nf++){
        int row = rw + kgrp*4 + r, col = nf*16 + ccol;
        outP[((size_t)(i0*KK + row))*HH + col] = (acc[nf][r]-mean)*inv*lnG[col] + lnB[col];
      }
    }
  }
}

// ---------------- fused FFN 128->512->128 + LN2 + mask_V ----------------
__global__ __launch_bounds__(256, 2) void enc_ffn(
    const float* __restrict__ X,                 // hVmid [N,128]
    const short* __restrict__ pkWin, const float* __restrict__ bin,
    const short* __restrict__ pkWout, const float* __restrict__ bout,
    const float* __restrict__ g2, const float* __restrict__ b2ln,
    const float* __restrict__ maskV,
    float* __restrict__ out)
{
  __shared__ short sT[64*512];   // XOR-swizzled: elem col ^ ((row&7)<<3)
  const int t = threadIdx.x, lane = t & 63, w = t >> 6;
  const int kgrp = lane >> 4, ccol = lane & 15;
  const int row0 = blockIdx.x*64;
  const int arow = row0 + w*16 + (lane & 15);
  // phase 1: T = gelu(X@Win + bin)
  f32x4 acc[32];
  #pragma unroll
  for (int nf=0;nf<32;nf++) acc[nf] = (f32x4){0,0,0,0};
  #pragma unroll
  for (int kt=0;kt<4;kt++){
    bf16x8 af = {0,0,0,0,0,0,0,0};
    if (arow < NN){
      const float4* p = (const float4*)(X + (size_t)arow*HH + kt*32 + kgrp*8);
      float4 v0 = p[0], v1 = p[1];
      af[0]=f2b(v0.x); af[1]=f2b(v0.y); af[2]=f2b(v0.z); af[3]=f2b(v0.w);
      af[4]=f2b(v1.x); af[5]=f2b(v1.y); af[6]=f2b(v1.z); af[7]=f2b(v1.w);
    }
    #pragma unroll
    for (int nf=0;nf<32;nf++){
      bf16x8 b = *(const bf16x8*)(pkWin + ((size_t)((kt<<5)+nf)*64 + lane)*8);
      acc[nf] = MFMA(af, b, acc[nf]);
    }
  }
  #pragma unroll
  for (int nf=0;nf<32;nf++){
    #pragma unroll
    for (int r=0;r<4;r++){
      int rl = w*16 + kgrp*4 + r, col = nf*16 + ccol;
      sT[rl*512 + (col ^ ((rl&7)<<3))] = f2b(gelu_fast(acc[nf][r] + bin[col]));
    }
  }
  // phase 2: out = T@Wout + bout, residual + LN2 + mask  (wave-local rows)
  f32x4 a2[8];
  #pragma unroll
  for (int nf=0;nf<8;nf++) a2[nf] = (f32x4){0,0,0,0};
  const int rl_a = w*16 + (lane & 15);
  #pragma unroll
  for (int kt=0;kt<16;kt++){
    int base = kt*32 + kgrp*8;
    bf16x8 af = *(const bf16x8*)(sT + rl_a*512 + (base ^ ((rl_a&7)<<3)));
    #pragma unroll
    for (int nf=0;nf<8;nf++){
      bf16x8 b = *(const bf16x8*)(pkWout + (((kt<<3)+nf)*64 + lane)*8);
      a2[nf] = MFMA(af, b, a2[nf]);
    }
  }
  float rsum[4] = {0,0,0,0}, rsq[4] = {0,0,0,0};
  #pragma unroll
  for (int nf=0;nf<8;nf++){
    #pragma unroll
    for (int r=0;r<4;r++){
      int grow = row0 + w*16 + kgrp*4 + r, col = nf*16 + ccol;
      float prev = (grow < NN) ? X[(size_t)grow*HH + col] : 0.f;
      float x = a2[nf][r] + bout[col] + prev;
      a2[nf][r] = x;
      rsum[r] += x; rsq[r] += x*x;
    }
  }
  #pragma unroll
  for (int off=1; off<16; off<<=1){
    #pragma unroll
    for (int r=0;r<4;r++){
      rsum[r] += __shfl_xor(rsum[r], off);
      rsq[r]  += __shfl_xor(rsq[r], off);
    }
  }
  #pragma unroll
  for (int r=0;r<4;r++){
    int grow = row0 + w*16 + kgrp*4 + r;
    float mean = rsum[r]*(1.f/128.f);
    float var  = rsq[r]*(1.f/128.f) - mean*mean;
    float inv  = rsqrtf(var + LN_EPS);
    float mv   = (grow < NN) ? maskV[grow] : 0.f;
    #pragma unroll
    for (int nf=0;nf<8;nf++){
      int col = nf*16 + ccol;
      if (grow < NN)
        out[(size_t)grow*HH + col] = mv * ((a2[nf][r]-mean)*inv*g2[col] + b2ln[col]);
    }
  }
}

// ---------------- host ----------------
extern "C" void kernel_launch(void* const* d_in, const int* in_sizes, int n_in,
                              void* d_out, int out_size, void* d_ws, size_t ws_size,
                              hipStream_t stream)
{
  const float* h_V   = (const float*)d_in[0];
  const float* h_E   = (const float*)d_in[1];
  const float* maskV = (const float*)d_in[2];
  const float* maskA = (const float*)d_in[3];
  const float* W1w  = (const float*)d_in[4];  const float* W1b  = (const float*)d_in[5];
  const float* W2w  = (const float*)d_in[6];  const float* W2b  = (const float*)d_in[7];
  const float* W3w  = (const float*)d_in[8];  const float* W3b  = (const float*)d_in[9];
  const float* W11w = (const float*)d_in[10]; const float* W11b = (const float*)d_in[11];
  const float* W12w = (const float*)d_in[12]; const float* W12b = (const float*)d_in[13];
  const float* W13w = (const float*)d_in[14]; const float* W13b = (const float*)d_in[15];
  const float* Winw = (const float*)d_in[16]; const float* Winb = (const float*)d_in[17];
  const float* Woutw= (const float*)d_in[18]; const float* Woutb= (const float*)d_in[19];
  const float* ln1g = (const float*)d_in[20]; const float* ln1b = (const float*)d_in[21];
  const float* ln2g = (const float*)d_in[22]; const float* ln2b = (const float*)d_in[23];
  const float* ln3g = (const float*)d_in[24]; const float* ln3b = (const float*)d_in[25];
  const int*   Eidx = (const int*)d_in[26];

  float* outV = (float*)d_out;                     // [N,128]
  float* outE = outV + (size_t)NN*HH;              // [N,K,128]

  char* ws = (char*)d_ws;
  short* pk = (short*)ws;
  const short* pkW1a  = pk + 0*16384;
  const short* pkW1c  = pk + 1*16384;
  const short* pkW1bb = pk + 2*16384;
  const short* pkW2   = pk + 3*16384;
  const short* pkW3   = pk + 4*16384;
  const short* pkW11a = pk + 5*16384;
  const short* pkW11c = pk + 6*16384;
  const short* pkW11bb= pk + 7*16384;
  const short* pkW12  = pk + 8*16384;
  const short* pkW13  = pk + 9*16384;
  const short* pkWin  = pk + 163840;
  const short* pkWout = pk + 229376;

  short* U1 = (short*)(ws + 1048576);
  short* Z1 = (short*)(ws + 6291456);
  short* U2 = (short*)(ws + 11534336);
  short* Z2 = (short*)(ws + 16777216);
  float* hVmid = (float*)(ws + 22020096);

  enc_pack<<<288, 256, 0, stream>>>(W1w, W2w, W3w, W11w, W12w, W13w, Winw, Woutw, pk);
  enc_proj<<<313, 256, 0, stream>>>(h_V, pkW1a, pkW1c, W1b, U1, Z1);
  enc_mlp3<0><<<NN/2, 256, 0, stream>>>(h_E, U1, Z1, Eidx, maskA, h_V,
                                        ln1g, ln1b, pkW1bb, pkW2, W2b, pkW3, W3b, hVmid);
  enc_ffn<<<313, 256, 0, stream>>>(hVmid, pkWin, Winb, pkWout, Woutb,
                                   ln2g, ln2b, maskV, outV);
  enc_proj<<<313, 256, 0, stream>>>(outV, pkW11a, pkW11c, W11b, U2, Z2);
  enc_mlp3<1><<<NN/2, 256, 0, stream>>>(h_E, U2, Z2, Eidx, nullptr, nullptr,
                                        ln3g, ln3b, pkW11bb, pkW12, W12b, pkW13, W13b, outE);
}